// Round 5
// baseline (370.803 us; speedup 1.0000x reference)
//
#include <hip/hip_runtime.h>

#define NN    100000   // N_NODES
#define F     64       // feature dim (= hidden dim)
#define NBUCK 391      // ceil(NN/256) buckets of 256 nodes
#define TILE  8192     // edges per binpack workgroup
#define CAP   6144     // node_sort LDS staging capacity (avg bucket ~3197)

// ---------------------------------------------------------------------------
// Per-WG LDS histogram of dst>>8, merged with one global atomic per bucket.
__global__ __launch_bounds__(256) void bucket_hist(const int* __restrict__ dst, int E,
                                                   int* __restrict__ bcnt) {
    __shared__ int h[NBUCK];
    for (int i = threadIdx.x; i < NBUCK; i += 256) h[i] = 0;
    __syncthreads();
    int stride = gridDim.x * 256;
    for (int e = blockIdx.x * 256 + threadIdx.x; e < E; e += stride)
        atomicAdd(&h[dst[e] >> 8], 1);
    __syncthreads();
    for (int i = threadIdx.x; i < NBUCK; i += 256)
        if (h[i]) atomicAdd(&bcnt[i], h[i]);
}

// Exclusive scan of 391 bucket counts (single WG); writes bbase + cursor init.
__global__ __launch_bounds__(512) void bucket_scan(const int* __restrict__ bcnt,
                                                   int* __restrict__ bbase,
                                                   int* __restrict__ cursor, int E) {
    __shared__ int s[512];
    int t = threadIdx.x;
    int v = (t < NBUCK) ? bcnt[t] : 0;
    s[t] = v;
    __syncthreads();
    for (int off = 1; off < 512; off <<= 1) {
        int u = (t >= off) ? s[t - off] : 0;
        __syncthreads();
        s[t] += u;
        __syncthreads();
    }
    if (t < NBUCK) {
        int ex = s[t] - v;
        bbase[t]  = ex;
        cursor[t] = ex;
    }
    if (t == 0) bbase[NBUCK] = E;
}

// ---------------------------------------------------------------------------
// Tile counting-sort into 391 coarse buckets with LDS staging + coalesced
// flush. packed edge = (src<<8) | (dst & 255)  (src<2^17, 256 nodes/bucket).
// ---------------------------------------------------------------------------
__global__ __launch_bounds__(1024) void binpack(const int* __restrict__ src,
                                                const int* __restrict__ dst, int E,
                                                int* __restrict__ cursor,
                                                unsigned* __restrict__ packed) {
    __shared__ int hist[NBUCK];
    __shared__ int lofs[NBUCK];
    __shared__ int gbase[NBUCK];
    __shared__ int lcur[NBUCK];
    __shared__ int ss[512];
    __shared__ unsigned stage[TILE];          // 32 KB
    __shared__ unsigned short sbuck[TILE];    // 16 KB
    int t  = threadIdx.x;
    int t0 = blockIdx.x * TILE;
    int n  = min(TILE, E - t0);

    for (int i = t; i < NBUCK; i += 1024) hist[i] = 0;
    __syncthreads();
    for (int i = t; i < n; i += 1024) atomicAdd(&hist[dst[t0 + i] >> 8], 1);
    __syncthreads();
    int v = 0;
    if (t < 512) { v = (t < NBUCK) ? hist[t] : 0; ss[t] = v; }
    __syncthreads();
    for (int off = 1; off < 512; off <<= 1) {
        int u = 0;
        if (t < 512 && t >= off) u = ss[t - off];
        __syncthreads();
        if (t < 512) ss[t] += u;
        __syncthreads();
    }
    if (t < NBUCK) {
        int ex = ss[t] - v;
        lofs[t] = ex;
        lcur[t] = ex;
        int c = hist[t];
        gbase[t] = c ? atomicAdd(&cursor[t], c) : 0;
    }
    __syncthreads();
    for (int i = t; i < n; i += 1024) {
        int d = dst[t0 + i];
        int b = d >> 8;
        int p = atomicAdd(&lcur[b], 1);
        stage[p] = ((unsigned)src[t0 + i] << 8) | (unsigned)(d & 255);
        sbuck[p] = (unsigned short)b;
    }
    __syncthreads();
    // coalesced flush: consecutive i in a bucket run -> consecutive global slots
    for (int i = t; i < n; i += 1024) {
        int b = sbuck[i];
        packed[gbase[b] + (i - lofs[b])] = stage[i];
    }
}

// ---------------------------------------------------------------------------
// Per-bucket LDS counting sort to full node order; emits row_ptr + dis.
// ---------------------------------------------------------------------------
__global__ __launch_bounds__(512) void node_sort(const unsigned* __restrict__ packed,
                                                 const int* __restrict__ bbase,
                                                 int* __restrict__ row_ptr,
                                                 int* __restrict__ srt,
                                                 float* __restrict__ dis, int E) {
    __shared__ int h[256];
    __shared__ int ex[256];
    __shared__ int lcur[256];
    __shared__ int stage[CAP];                // 24 KB
    int b = blockIdx.x, t = threadIdx.x;
    int nbase = b << 8;
    int nloc = min(256, NN - nbase);
    int beg = bbase[b], end = bbase[b + 1];
    int n = end - beg;

    if (t < 256) h[t] = 0;
    __syncthreads();
    for (int i = beg + t; i < end; i += 512)
        atomicAdd(&h[packed[i] & 255u], 1);
    __syncthreads();
    int v = 0;
    if (t < 256) { v = h[t]; ex[t] = v; }
    __syncthreads();
    for (int off = 1; off < 256; off <<= 1) {
        int u = 0;
        if (t < 256 && t >= off) u = ex[t - off];
        __syncthreads();
        if (t < 256) ex[t] += u;
        __syncthreads();
    }
    if (t < nloc) {
        int e0 = ex[t] - v;
        row_ptr[nbase + t] = beg + e0;
        lcur[t] = e0;
        dis[nbase + t] = rsqrtf((float)v + 1.0f);   // +1 = self-loop
    }
    if (b == 0 && t == 0) row_ptr[NN] = E;
    __syncthreads();
    if (n <= CAP) {
        for (int i = beg + t; i < end; i += 512) {
            unsigned p = packed[i];
            int pos = atomicAdd(&lcur[p & 255u], 1);
            stage[pos] = (int)(p >> 8);
        }
        __syncthreads();
        for (int i = t; i < n; i += 512) srt[beg + i] = stage[i];
    } else {
        for (int i = beg + t; i < end; i += 512) {
            unsigned p = packed[i];
            int pos = atomicAdd(&lcur[p & 255u], 1);
            srt[beg + pos] = (int)(p >> 8);
        }
    }
}

// ---------------------------------------------------------------------------
// A = (X @ W) * dis[row].  16 rows/block, 256 threads, 4 outputs/thread.
// ---------------------------------------------------------------------------
__global__ __launch_bounds__(256) void gemm_scale(const float* __restrict__ X,
                                                  const float* __restrict__ W,
                                                  const float* __restrict__ dis,
                                                  float* __restrict__ A) {
    __shared__ float wl[64][64];
    __shared__ float xl[16][64];
    int tid = threadIdx.x;
    for (int t = tid; t < 64 * 64; t += 256) wl[t >> 6][t & 63] = W[t];
    size_t base = (size_t)blockIdx.x * 16 * F;
    for (int t = tid; t < 16 * 64; t += 256) xl[t >> 6][t & 63] = X[base + t];
    __syncthreads();

    int col = tid & 63;
    int w   = tid >> 6;
    float a0 = 0.f, a1 = 0.f, a2 = 0.f, a3 = 0.f;
#pragma unroll
    for (int k = 0; k < 64; ++k) {
        float wk = wl[k][col];
        a0 = fmaf(xl[w * 4 + 0][k], wk, a0);
        a1 = fmaf(xl[w * 4 + 1][k], wk, a1);
        a2 = fmaf(xl[w * 4 + 2][k], wk, a2);
        a3 = fmaf(xl[w * 4 + 3][k], wk, a3);
    }
    int row = blockIdx.x * 16 + w * 4;
    float acc[4] = {a0, a1, a2, a3};
#pragma unroll
    for (int q = 0; q < 4; ++q)
        A[(size_t)(row + q) * F + col] = acc[q] * dis[row + q];
}

// ---------------------------------------------------------------------------
// Wave-per-node gather: lane = feature, 16-deep predicated batches.
// Edge list padded to x16 with the node's own row, compensated exactly by
// acc -= pad*self (error ~ulp). 16 outstanding 256 B row-reads per wave.
// srt slab is padded >= E+15, so the speculative srt[e] reads are in-bounds.
// ---------------------------------------------------------------------------
__device__ __forceinline__ float gather16(const float* __restrict__ A,
                                          const int* __restrict__ srt,
                                          int beg, int end, int node, int lane) {
    const float self = A[(size_t)node * F + lane];
    float acc = self;                          // self-loop seed
    for (int j = beg; j < end; j += 16) {
        float v[16];
#pragma unroll
        for (int k = 0; k < 16; ++k) {
            int e   = j + k;
            int idx = (e < end) ? srt[e] : node;
            v[k] = A[(size_t)idx * F + lane];
        }
        float s0 = (v[0] + v[1]) + (v[2] + v[3]);
        float s1 = (v[4] + v[5]) + (v[6] + v[7]);
        float s2 = (v[8] + v[9]) + (v[10] + v[11]);
        float s3 = (v[12] + v[13]) + (v[14] + v[15]);
        acc += (s0 + s1) + (s2 + s3);
    }
    int pad = (16 - ((end - beg) & 15)) & 15;
    acc -= (float)pad * self;
    return acc;
}

// Aggregation with fused bias(+ReLU) epilogue. 4 nodes / 256-thread block.
__global__ __launch_bounds__(256) void agg_out(const float* __restrict__ A,
                                               const int* __restrict__ row_ptr,
                                               const int* __restrict__ srt,
                                               const float* __restrict__ dis,
                                               const float* __restrict__ bias,
                                               float* __restrict__ out, int do_relu) {
    int lane = threadIdx.x & 63;
    int node = blockIdx.x * 4 + (threadIdx.x >> 6);
    int beg = row_ptr[node], end = row_ptr[node + 1];
    float acc = gather16(A, srt, beg, end, node, lane);
    float v = fmaf(dis[node], acc, bias[lane]);
    if (do_relu) v = fmaxf(v, 0.f);
    out[(size_t)node * F + lane] = v;
}

// ---------------------------------------------------------------------------
// Fused layer-boundary kernel: aggregate layer 1 (h = relu(b1 + dis*acc)),
// round-trip h through LDS, then A2 = (h @ W2) * dis in-block.
// 16 nodes (= one gemm tile) per 1024-thread block; wave w <-> node/row w.
// ---------------------------------------------------------------------------
__global__ __launch_bounds__(1024) void agg_gemm(const float* __restrict__ A1,
                                                 const int* __restrict__ row_ptr,
                                                 const int* __restrict__ srt,
                                                 const float* __restrict__ dis,
                                                 const float* __restrict__ b1,
                                                 const float* __restrict__ W2,
                                                 float* __restrict__ A2) {
    __shared__ float wl[64][64];   // 16 KB
    __shared__ float hl[16][64];   // 4 KB
    int t = threadIdx.x;
    for (int i = t; i < 64 * 64; i += 1024) wl[i >> 6][i & 63] = W2[i];
    int lane = t & 63;
    int w    = t >> 6;                         // wave id = node-in-tile = row
    int node = blockIdx.x * 16 + w;
    int beg = row_ptr[node], end = row_ptr[node + 1];
    float dv = dis[node];
    float acc = gather16(A1, srt, beg, end, node, lane);
    float h = fmaf(dv, acc, b1[lane]);
    hl[w][lane] = fmaxf(h, 0.f);               // ReLU
    __syncthreads();
    float a = 0.f;
#pragma unroll
    for (int k = 0; k < 64; ++k)
        a = fmaf(hl[w][k], wl[k][lane], a);    // hl: broadcast; wl: 2-way free
    A2[(size_t)node * F + lane] = a * dv;
}

extern "C" void kernel_launch(void* const* d_in, const int* in_sizes, int n_in,
                              void* d_out, int out_size, void* d_ws, size_t ws_size,
                              hipStream_t stream) {
    const float* x  = (const float*)d_in[0];
    const int*   ei = (const int*)d_in[1];   // [2,E]: src = ei[0:E], dst = ei[E:2E]
    const float* W1 = (const float*)d_in[2];
    const float* b1 = (const float*)d_in[3];
    const float* W2 = (const float*)d_in[4];
    const float* b2 = (const float*)d_in[5];
    float* out = (float*)d_out;
    int E = in_sizes[1] / 2;
    const int* src = ei;
    const int* dst = ei + E;

    // workspace layout (4 B elements)
    int*   ws_i    = (int*)d_ws;
    int*   bcnt    = ws_i + 0;                 // [391]
    int*   bbase   = ws_i + 512;               // [392]
    int*   cursor  = ws_i + 1024;              // [391]
    int*   row_ptr = ws_i + 2048;              // [100001]
    float* dis     = (float*)(ws_i + 102400);  // [100000]
    int*   srt     = ws_i + 202752;            // [E] (+pad >= 15 for speculation)
    size_t epad    = ((size_t)E + 511) & ~(size_t)511;
    float* A1      = (float*)(ws_i + 202752 + epad);              // [NN*64]
    float* A2      = A1 + (size_t)NN * F;                         // [NN*64]
    // packed aliases A2's slab: dead before A2 is first written (fused path),
    // or sits in its own slot on the fallback path.
    size_t need_fused = ((size_t)202752 + epad + 2ull * NN * F) * 4ull;
    bool fused = (ws_size >= need_fused);
    unsigned* packed = fused ? (unsigned*)A2 : (unsigned*)(ws_i + 202752 + epad);
    if (!fused) A1 = (float*)(ws_i + 202752 + 2 * epad);          // round-4 layout

    // ---- edge preprocessing (once; shared by both layers) ----
    hipMemsetAsync(bcnt, 0, NBUCK * sizeof(int), stream);
    bucket_hist<<<512, 256, 0, stream>>>(dst, E, bcnt);
    bucket_scan<<<1, 512, 0, stream>>>(bcnt, bbase, cursor, E);
    binpack<<<(E + TILE - 1) / TILE, 1024, 0, stream>>>(src, dst, E, cursor, packed);
    node_sort<<<NBUCK, 512, 0, stream>>>(packed, bbase, row_ptr, srt, dis, E);

    if (fused) {
        gemm_scale<<<NN / 16, 256, 0, stream>>>(x, W1, dis, A1);
        agg_gemm<<<NN / 16, 1024, 0, stream>>>(A1, row_ptr, srt, dis, b1, W2, A2);
        agg_out<<<NN / 4, 256, 0, stream>>>(A2, row_ptr, srt, dis, b2, out, 0);
    } else {
        // fallback: round-4 structure (h staged in d_out)
        gemm_scale<<<NN / 16, 256, 0, stream>>>(x, W1, dis, A1);
        agg_out<<<NN / 4, 256, 0, stream>>>(A1, row_ptr, srt, dis, b1, out, 1);
        gemm_scale<<<NN / 16, 256, 0, stream>>>(out, W2, dis, A1);
        agg_out<<<NN / 4, 256, 0, stream>>>(A1, row_ptr, srt, dis, b2, out, 0);
    }
}

// Round 6
// 274.727 us; speedup vs baseline: 1.3497x; 1.3497x over previous
//
#include <hip/hip_runtime.h>

#define NN    100000   // N_NODES
#define F     64       // feature dim (= hidden dim)
#define NBUCK 391      // ceil(NN/256) buckets of 256 nodes
#define CAPB  4096     // per-bucket edge capacity (mean 3197, 16-sigma margin)
#define TILE  4096     // edges per binpack tile

// workspace offsets (4-byte elements)
#define O_CURSOR 0          // int[391]
#define O_ROWPTR 512        // int[100000]  absolute index into srt
#define O_DEG    100864     // int[100000]
#define O_DIS    201216     // float[100000]
#define O_PACKED 301568     // uint[391*4096]
#define O_SRT    1903104    // int[391*4096 + 64]
#define O_A      3504768    // float[NN*64], 256 B aligned

// ---------------------------------------------------------------------------
// Tile counting-sort into 391 bucket-strided regions. One global atomic per
// bucket per tile reserves space at implicit base b*CAPB (no global scan
// needed). packed edge = (src<<8) | (dst & 255).
// ---------------------------------------------------------------------------
__global__ __launch_bounds__(512) void binpack(const int* __restrict__ src,
                                               const int* __restrict__ dst, int E,
                                               int* __restrict__ cursor,
                                               unsigned* __restrict__ packed) {
    __shared__ int hist[NBUCK];
    __shared__ int lofs[NBUCK];
    __shared__ int gbase[NBUCK];
    __shared__ int lcur[NBUCK];
    __shared__ int wsum[8];
    __shared__ unsigned stage[TILE];          // 16 KB
    __shared__ unsigned short sbuck[TILE];    // 8 KB
    int t  = threadIdx.x;
    int t0 = blockIdx.x * TILE;
    int n  = min(TILE, E - t0);

    if (t < NBUCK) hist[t] = 0;
    __syncthreads();
    for (int i = t; i < n; i += 512) atomicAdd(&hist[dst[t0 + i] >> 8], 1);
    __syncthreads();
    // wave-shuffle exclusive scan over 391 entries (2 barriers total)
    int lane = t & 63, w = t >> 6;
    int v = (t < NBUCK) ? hist[t] : 0;
    int s = v;
#pragma unroll
    for (int off = 1; off < 64; off <<= 1) {
        int u = __shfl_up(s, off, 64);
        if (lane >= off) s += u;
    }
    if (lane == 63) wsum[w] = s;
    __syncthreads();
    if (t == 0) {
        int run = 0;
#pragma unroll
        for (int i = 0; i < 8; ++i) { int c = wsum[i]; wsum[i] = run; run += c; }
    }
    __syncthreads();
    if (t < NBUCK) {
        int ex = s - v + wsum[w];             // exclusive within tile
        lofs[t] = ex;
        lcur[t] = ex;
        gbase[t] = t * CAPB + (v ? atomicAdd(&cursor[t], v) : 0);
    }
    __syncthreads();
    // place into LDS staging, locally bucket-sorted
    for (int i = t; i < n; i += 512) {
        int d = dst[t0 + i];
        int b = d >> 8;
        int p = atomicAdd(&lcur[b], 1);
        stage[p] = ((unsigned)src[t0 + i] << 8) | (unsigned)(d & 255);
        sbuck[p] = (unsigned short)b;
    }
    __syncthreads();
    // coalesced flush: consecutive i in a bucket run -> consecutive global slots
    for (int i = t; i < n; i += 512) {
        int b = sbuck[i];
        packed[gbase[b] + (i - lofs[b])] = stage[i];
    }
}

// ---------------------------------------------------------------------------
// Per-bucket LDS counting sort to node order; emits row_ptr (absolute), deg,
// dis = rsqrt(deg+1). srt stays bucket-strided (gaps are fine).
// ---------------------------------------------------------------------------
__global__ __launch_bounds__(512) void node_sort(const unsigned* __restrict__ packed,
                                                 const int* __restrict__ cursor,
                                                 int* __restrict__ row_ptr,
                                                 int* __restrict__ deg,
                                                 float* __restrict__ dis,
                                                 int* __restrict__ srt) {
    __shared__ int h[256];
    __shared__ int lcur[256];
    __shared__ int wsum[4];
    __shared__ int stage[CAPB];               // 16 KB
    int b = blockIdx.x, t = threadIdx.x;
    int nbase = b << 8;
    int nloc = min(256, NN - nbase);
    int beg = b * CAPB;
    int n = cursor[b];                        // bucket edge count

    if (t < 256) h[t] = 0;
    __syncthreads();
    for (int i = t; i < n; i += 512)
        atomicAdd(&h[packed[beg + i] & 255u], 1);
    __syncthreads();
    // wave-shuffle exclusive scan over 256 entries
    int lane = t & 63, w = t >> 6;
    int v = 0, s = 0;
    if (t < 256) { v = h[t]; s = v; }
#pragma unroll
    for (int off = 1; off < 64; off <<= 1) {
        int u = __shfl_up(s, off, 64);
        if (lane >= off) s += u;
    }
    if (t < 256 && lane == 63) wsum[w] = s;
    __syncthreads();
    if (t == 0) {
        int run = 0;
#pragma unroll
        for (int i = 0; i < 4; ++i) { int c = wsum[i]; wsum[i] = run; run += c; }
    }
    __syncthreads();
    if (t < 256) {
        int e0 = s - v + wsum[w];             // exclusive
        lcur[t] = e0;
        if (t < nloc) {
            row_ptr[nbase + t] = beg + e0;
            deg[nbase + t]     = v;
            dis[nbase + t]     = rsqrtf((float)v + 1.0f);   // +1 = self-loop
        }
    }
    __syncthreads();
    for (int i = t; i < n; i += 512) {
        unsigned p = packed[beg + i];
        int pos = atomicAdd(&lcur[p & 255u], 1);
        stage[pos] = (int)(p >> 8);
    }
    __syncthreads();
    for (int i = t; i < n; i += 512) srt[beg + i] = stage[i];
}

// ---------------------------------------------------------------------------
// A = (X @ W) * dis[row].  16 rows/block, 256 threads, 4 outputs/thread.
// ---------------------------------------------------------------------------
__global__ __launch_bounds__(256) void gemm_scale(const float* __restrict__ X,
                                                  const float* __restrict__ W,
                                                  const float* __restrict__ dis,
                                                  float* __restrict__ A) {
    __shared__ float wl[64][64];
    __shared__ float xl[16][64];
    int tid = threadIdx.x;
    for (int t = tid; t < 64 * 64; t += 256) wl[t >> 6][t & 63] = W[t];
    size_t base = (size_t)blockIdx.x * 16 * F;
    for (int t = tid; t < 16 * 64; t += 256) xl[t >> 6][t & 63] = X[base + t];
    __syncthreads();

    int col = tid & 63;
    int w   = tid >> 6;
    float a0 = 0.f, a1 = 0.f, a2 = 0.f, a3 = 0.f;
#pragma unroll
    for (int k = 0; k < 64; ++k) {
        float wk = wl[k][col];
        a0 = fmaf(xl[w * 4 + 0][k], wk, a0);
        a1 = fmaf(xl[w * 4 + 1][k], wk, a1);
        a2 = fmaf(xl[w * 4 + 2][k], wk, a2);
        a3 = fmaf(xl[w * 4 + 3][k], wk, a3);
    }
    int row = blockIdx.x * 16 + w * 4;
    float acc[4] = {a0, a1, a2, a3};
#pragma unroll
    for (int q = 0; q < 4; ++q)
        A[(size_t)(row + q) * F + col] = acc[q] * dis[row + q];
}

// ---------------------------------------------------------------------------
// Gather aggregation + fused bias(+ReLU). 16 lanes/node (float4/lane),
// 16 nodes per 256-thread block, 6250 blocks. 8-deep predicated batches:
// pad slots read the node's own row (L1-hot), compensated by acc -= pad*self.
// 8 outstanding dwordx4 per group = up to 32 per wave.
// ---------------------------------------------------------------------------
__global__ __launch_bounds__(256) void agg_out(const float4* __restrict__ A4,
                                               const int* __restrict__ row_ptr,
                                               const int* __restrict__ deg,
                                               const int* __restrict__ srt,
                                               const float* __restrict__ dis,
                                               const float* __restrict__ bias,
                                               float4* __restrict__ out, int do_relu) {
    int sub  = threadIdx.x & 15;
    int node = blockIdx.x * 16 + (threadIdx.x >> 4);
    int beg = row_ptr[node];
    int cnt = deg[node];
    int end = beg + cnt;
    const float4 self = A4[(size_t)node * 16 + sub];
    float4 acc = self;                        // self-loop seed
    for (int j = beg; j < end; j += 8) {
        float4 vv[8];
#pragma unroll
        for (int k = 0; k < 8; ++k) {
            int e   = j + k;
            int idx = (e < end) ? srt[e] : node;   // srt region has >=7 pad slots
            vv[k] = A4[(size_t)idx * 16 + sub];
        }
        acc.x += ((vv[0].x + vv[1].x) + (vv[2].x + vv[3].x)) +
                 ((vv[4].x + vv[5].x) + (vv[6].x + vv[7].x));
        acc.y += ((vv[0].y + vv[1].y) + (vv[2].y + vv[3].y)) +
                 ((vv[4].y + vv[5].y) + (vv[6].y + vv[7].y));
        acc.z += ((vv[0].z + vv[1].z) + (vv[2].z + vv[3].z)) +
                 ((vv[4].z + vv[5].z) + (vv[6].z + vv[7].z));
        acc.w += ((vv[0].w + vv[1].w) + (vv[2].w + vv[3].w)) +
                 ((vv[4].w + vv[5].w) + (vv[6].w + vv[7].w));
    }
    float fp = (float)((8 - (cnt & 7)) & 7);  // exact pad compensation
    acc.x -= fp * self.x;
    acc.y -= fp * self.y;
    acc.z -= fp * self.z;
    acc.w -= fp * self.w;
    float dv = dis[node];
    float4 bb = ((const float4*)bias)[sub];
    float4 o;
    o.x = fmaf(dv, acc.x, bb.x);
    o.y = fmaf(dv, acc.y, bb.y);
    o.z = fmaf(dv, acc.z, bb.z);
    o.w = fmaf(dv, acc.w, bb.w);
    if (do_relu) {
        o.x = fmaxf(o.x, 0.f); o.y = fmaxf(o.y, 0.f);
        o.z = fmaxf(o.z, 0.f); o.w = fmaxf(o.w, 0.f);
    }
    out[(size_t)node * 16 + sub] = o;
}

extern "C" void kernel_launch(void* const* d_in, const int* in_sizes, int n_in,
                              void* d_out, int out_size, void* d_ws, size_t ws_size,
                              hipStream_t stream) {
    const float* x  = (const float*)d_in[0];
    const int*   ei = (const int*)d_in[1];   // [2,E]: src = ei[0:E], dst = ei[E:2E]
    const float* W1 = (const float*)d_in[2];
    const float* b1 = (const float*)d_in[3];
    const float* W2 = (const float*)d_in[4];
    const float* b2 = (const float*)d_in[5];
    float* out = (float*)d_out;
    int E = in_sizes[1] / 2;
    const int* src = ei;
    const int* dst = ei + E;

    int*      ws_i    = (int*)d_ws;
    int*      cursor  = ws_i + O_CURSOR;
    int*      row_ptr = ws_i + O_ROWPTR;
    int*      deg     = ws_i + O_DEG;
    float*    dis     = (float*)(ws_i + O_DIS);
    unsigned* packed  = (unsigned*)(ws_i + O_PACKED);
    int*      srt     = ws_i + O_SRT;
    float*    A       = (float*)(ws_i + O_A);

    // ---- edge preprocessing (once; shared by both layers) ----
    hipMemsetAsync(cursor, 0, NBUCK * sizeof(int), stream);
    binpack<<<(E + TILE - 1) / TILE, 512, 0, stream>>>(src, dst, E, cursor, packed);
    node_sort<<<NBUCK, 512, 0, stream>>>(packed, cursor, row_ptr, deg, dis, srt);

    // ---- layer 1 ----
    gemm_scale<<<NN / 16, 256, 0, stream>>>(x, W1, dis, A);
    agg_out<<<NN / 16, 256, 0, stream>>>((const float4*)A, row_ptr, deg, srt, dis,
                                         b1, (float4*)out, 1);
    // ---- layer 2 (reads h from d_out, overwrites d_out) ----
    gemm_scale<<<NN / 16, 256, 0, stream>>>(out, W2, dis, A);
    agg_out<<<NN / 16, 256, 0, stream>>>((const float4*)A, row_ptr, deg, srt, dis,
                                         b2, (float4*)out, 0);
}

// Round 7
// 265.629 us; speedup vs baseline: 1.3959x; 1.0343x over previous
//
#include <hip/hip_runtime.h>

#define NN    100000   // N_NODES
#define F     64       // feature dim (= hidden dim)
#define NBUCK 391      // ceil(NN/256) buckets of 256 nodes
#define CAPB  4096     // per-bucket edge capacity (mean 3197, 16-sigma margin)
#define TILE  4096     // edges per binpack tile

// workspace offsets (4-byte elements)
#define O_CURSOR 0          // int[391]
#define O_ROWPTR 512        // int[100000]  absolute index into srt
#define O_DEG    100864     // int[100000]
#define O_DIS    201216     // float[100000]
#define O_PACKED 301568     // uint[391*4096]
#define O_SRT    1903104    // int[391*4096 + 64]
#define O_A      3504768    // float[NN*64], 256 B aligned

// ---------------------------------------------------------------------------
// Tile counting-sort into 391 bucket-strided regions. One global atomic per
// bucket per tile reserves space at implicit base b*CAPB. packed edge =
// (src<<8) | (dst & 255).
// ---------------------------------------------------------------------------
__global__ __launch_bounds__(512) void binpack(const int* __restrict__ src,
                                               const int* __restrict__ dst, int E,
                                               int* __restrict__ cursor,
                                               unsigned* __restrict__ packed) {
    __shared__ int hist[NBUCK];
    __shared__ int lofs[NBUCK];
    __shared__ int gbase[NBUCK];
    __shared__ int lcur[NBUCK];
    __shared__ int wsum[8];
    __shared__ unsigned stage[TILE];          // 16 KB
    __shared__ unsigned short sbuck[TILE];    // 8 KB
    int t  = threadIdx.x;
    int t0 = blockIdx.x * TILE;
    int n  = min(TILE, E - t0);

    if (t < NBUCK) hist[t] = 0;
    __syncthreads();
    for (int i = t; i < n; i += 512) atomicAdd(&hist[dst[t0 + i] >> 8], 1);
    __syncthreads();
    // wave-shuffle exclusive scan over 391 entries (2 barriers total)
    int lane = t & 63, w = t >> 6;
    int v = (t < NBUCK) ? hist[t] : 0;
    int s = v;
#pragma unroll
    for (int off = 1; off < 64; off <<= 1) {
        int u = __shfl_up(s, off, 64);
        if (lane >= off) s += u;
    }
    if (lane == 63) wsum[w] = s;
    __syncthreads();
    if (t == 0) {
        int run = 0;
#pragma unroll
        for (int i = 0; i < 8; ++i) { int c = wsum[i]; wsum[i] = run; run += c; }
    }
    __syncthreads();
    if (t < NBUCK) {
        int ex = s - v + wsum[w];             // exclusive within tile
        lofs[t] = ex;
        lcur[t] = ex;
        gbase[t] = t * CAPB + (v ? atomicAdd(&cursor[t], v) : 0);
    }
    __syncthreads();
    for (int i = t; i < n; i += 512) {
        int d = dst[t0 + i];
        int b = d >> 8;
        int p = atomicAdd(&lcur[b], 1);
        stage[p] = ((unsigned)src[t0 + i] << 8) | (unsigned)(d & 255);
        sbuck[p] = (unsigned short)b;
    }
    __syncthreads();
    // coalesced flush: consecutive i in a bucket run -> consecutive global slots
    for (int i = t; i < n; i += 512) {
        int b = sbuck[i];
        packed[gbase[b] + (i - lofs[b])] = stage[i];
    }
}

// ---------------------------------------------------------------------------
// Per-bucket LDS counting sort to node order; emits row_ptr (absolute), deg,
// dis = rsqrt(deg+1). srt stays bucket-strided (gaps are fine).
// ---------------------------------------------------------------------------
__global__ __launch_bounds__(512) void node_sort(const unsigned* __restrict__ packed,
                                                 const int* __restrict__ cursor,
                                                 int* __restrict__ row_ptr,
                                                 int* __restrict__ deg,
                                                 float* __restrict__ dis,
                                                 int* __restrict__ srt) {
    __shared__ int h[256];
    __shared__ int lcur[256];
    __shared__ int wsum[4];
    __shared__ int stage[CAPB];               // 16 KB
    int b = blockIdx.x, t = threadIdx.x;
    int nbase = b << 8;
    int nloc = min(256, NN - nbase);
    int beg = b * CAPB;
    int n = cursor[b];                        // bucket edge count

    if (t < 256) h[t] = 0;
    __syncthreads();
    for (int i = t; i < n; i += 512)
        atomicAdd(&h[packed[beg + i] & 255u], 1);
    __syncthreads();
    int lane = t & 63, w = t >> 6;
    int v = 0, s = 0;
    if (t < 256) { v = h[t]; s = v; }
#pragma unroll
    for (int off = 1; off < 64; off <<= 1) {
        int u = __shfl_up(s, off, 64);
        if (lane >= off) s += u;
    }
    if (t < 256 && lane == 63) wsum[w] = s;
    __syncthreads();
    if (t == 0) {
        int run = 0;
#pragma unroll
        for (int i = 0; i < 4; ++i) { int c = wsum[i]; wsum[i] = run; run += c; }
    }
    __syncthreads();
    if (t < 256) {
        int e0 = s - v + wsum[w];             // exclusive
        lcur[t] = e0;
        if (t < nloc) {
            row_ptr[nbase + t] = beg + e0;
            deg[nbase + t]     = v;
            dis[nbase + t]     = rsqrtf((float)v + 1.0f);   // +1 = self-loop
        }
    }
    __syncthreads();
    for (int i = t; i < n; i += 512) {
        unsigned p = packed[beg + i];
        int pos = atomicAdd(&lcur[p & 255u], 1);
        stage[pos] = (int)(p >> 8);
    }
    __syncthreads();
    for (int i = t; i < n; i += 512) srt[beg + i] = stage[i];
}

// ---------------------------------------------------------------------------
// A = (X @ W) * dis[row].  VALU-only inner loop: W column in 64 VGPRs/lane
// (one-time LDS stage), x broadcast via v_readlane -> SGPR, v_fmac per k.
// 4 waves/block, 4 rows/wave, 16 rows/block. Zero LDS traffic in the loop.
// ---------------------------------------------------------------------------
__global__ __launch_bounds__(256) void gemm_scale(const float* __restrict__ X,
                                                  const float* __restrict__ W,
                                                  const float* __restrict__ dis,
                                                  float* __restrict__ A) {
    __shared__ float wl[64 * 64];             // 16 KB, [k][col]
    int t = threadIdx.x;
    for (int i = t; i < 64 * 64; i += 256) wl[i] = W[i];
    __syncthreads();
    int lane = t & 63;
    int w    = t >> 6;
    float Wreg[64];
#pragma unroll
    for (int k = 0; k < 64; ++k) Wreg[k] = wl[k * 64 + lane];  // 2-way alias: free

    int row0 = blockIdx.x * 16 + w * 4;
    const float* xp = X + (size_t)row0 * F;
    float xa = xp[lane];
    float xb = xp[64 + lane];
    float xc = xp[128 + lane];
    float xd = xp[192 + lane];
    float a0 = 0.f, a1 = 0.f, a2 = 0.f, a3 = 0.f;
#pragma unroll
    for (int k = 0; k < 64; ++k) {
        float wv = Wreg[k];
        a0 = fmaf(__uint_as_float(__builtin_amdgcn_readlane(__float_as_uint(xa), k)), wv, a0);
        a1 = fmaf(__uint_as_float(__builtin_amdgcn_readlane(__float_as_uint(xb), k)), wv, a1);
        a2 = fmaf(__uint_as_float(__builtin_amdgcn_readlane(__float_as_uint(xc), k)), wv, a2);
        a3 = fmaf(__uint_as_float(__builtin_amdgcn_readlane(__float_as_uint(xd), k)), wv, a3);
    }
    float* ap = A + (size_t)row0 * F;
    ap[lane]       = a0 * dis[row0];
    ap[64 + lane]  = a1 * dis[row0 + 1];
    ap[128 + lane] = a2 * dis[row0 + 2];
    ap[192 + lane] = a3 * dis[row0 + 3];
}

// ---------------------------------------------------------------------------
// Gather aggregation + fused bias(+ReLU) — round-4 proven structure.
// 16 lanes/node (float4/lane), 16 nodes per 256-thread block, 4-deep ILP.
// ---------------------------------------------------------------------------
__global__ __launch_bounds__(256) void agg_out(const float4* __restrict__ A4,
                                               const int* __restrict__ row_ptr,
                                               const int* __restrict__ deg,
                                               const int* __restrict__ srt,
                                               const float* __restrict__ dis,
                                               const float* __restrict__ bias,
                                               float4* __restrict__ out, int do_relu) {
    int sub  = threadIdx.x & 15;
    int node = blockIdx.x * 16 + (threadIdx.x >> 4);
    int beg = row_ptr[node];
    int end = beg + deg[node];
    float4 acc = A4[(size_t)node * 16 + sub];       // self-loop seed
    int j = beg;
    for (; j + 4 <= end; j += 4) {
        int s0 = srt[j], s1 = srt[j + 1], s2 = srt[j + 2], s3 = srt[j + 3];
        float4 v0 = A4[(size_t)s0 * 16 + sub];
        float4 v1 = A4[(size_t)s1 * 16 + sub];
        float4 v2 = A4[(size_t)s2 * 16 + sub];
        float4 v3 = A4[(size_t)s3 * 16 + sub];
        acc.x += (v0.x + v1.x) + (v2.x + v3.x);
        acc.y += (v0.y + v1.y) + (v2.y + v3.y);
        acc.z += (v0.z + v1.z) + (v2.z + v3.z);
        acc.w += (v0.w + v1.w) + (v2.w + v3.w);
    }
    for (; j < end; ++j) {
        float4 v0 = A4[(size_t)srt[j] * 16 + sub];
        acc.x += v0.x; acc.y += v0.y; acc.z += v0.z; acc.w += v0.w;
    }
    float dv = dis[node];
    float4 bb = ((const float4*)bias)[sub];
    float4 o;
    o.x = fmaf(dv, acc.x, bb.x);
    o.y = fmaf(dv, acc.y, bb.y);
    o.z = fmaf(dv, acc.z, bb.z);
    o.w = fmaf(dv, acc.w, bb.w);
    if (do_relu) {
        o.x = fmaxf(o.x, 0.f); o.y = fmaxf(o.y, 0.f);
        o.z = fmaxf(o.z, 0.f); o.w = fmaxf(o.w, 0.f);
    }
    out[(size_t)node * 16 + sub] = o;
}

extern "C" void kernel_launch(void* const* d_in, const int* in_sizes, int n_in,
                              void* d_out, int out_size, void* d_ws, size_t ws_size,
                              hipStream_t stream) {
    const float* x  = (const float*)d_in[0];
    const int*   ei = (const int*)d_in[1];   // [2,E]: src = ei[0:E], dst = ei[E:2E]
    const float* W1 = (const float*)d_in[2];
    const float* b1 = (const float*)d_in[3];
    const float* W2 = (const float*)d_in[4];
    const float* b2 = (const float*)d_in[5];
    float* out = (float*)d_out;
    int E = in_sizes[1] / 2;
    const int* src = ei;
    const int* dst = ei + E;

    int*      ws_i    = (int*)d_ws;
    int*      cursor  = ws_i + O_CURSOR;
    int*      row_ptr = ws_i + O_ROWPTR;
    int*      deg     = ws_i + O_DEG;
    float*    dis     = (float*)(ws_i + O_DIS);
    unsigned* packed  = (unsigned*)(ws_i + O_PACKED);
    int*      srt     = ws_i + O_SRT;
    float*    A       = (float*)(ws_i + O_A);

    // ---- edge preprocessing (once; shared by both layers) ----
    hipMemsetAsync(cursor, 0, NBUCK * sizeof(int), stream);
    binpack<<<(E + TILE - 1) / TILE, 512, 0, stream>>>(src, dst, E, cursor, packed);
    node_sort<<<NBUCK, 512, 0, stream>>>(packed, cursor, row_ptr, deg, dis, srt);

    // ---- layer 1 ----
    gemm_scale<<<NN / 16, 256, 0, stream>>>(x, W1, dis, A);
    agg_out<<<NN / 16, 256, 0, stream>>>((const float4*)A, row_ptr, deg, srt, dis,
                                         b1, (float4*)out, 1);
    // ---- layer 2 (reads h from d_out, overwrites d_out) ----
    gemm_scale<<<NN / 16, 256, 0, stream>>>(out, W2, dis, A);
    agg_out<<<NN / 16, 256, 0, stream>>>((const float4*)A, row_ptr, deg, srt, dis,
                                         b2, (float4*)out, 0);
}

// Round 8
// 231.118 us; speedup vs baseline: 1.6044x; 1.1493x over previous
//
#include <hip/hip_runtime.h>

#define NN    100000   // N_NODES
#define F     64       // feature dim (= hidden dim)
#define NBUCK 391      // ceil(NN/256) buckets of 256 nodes
#define CAPB  4096     // per-bucket edge capacity (mean 3197, 16-sigma margin)
#define TILE  4096     // edges per binpack tile

// workspace offsets (4-byte elements)
#define O_CURSOR 0          // int[391]
#define O_ROWPTR 512        // int[100000]  absolute index into srt
#define O_DEG    100864     // int[100000]
#define O_DIS    201216     // float[100000]
#define O_PACKED 301568     // uint[391*4096]
#define O_SRT    1903104    // int[391*4096 + 64]
#define O_AH     3504768    // uint[NN*32]: bf16-packed A rows (128 B/row)

// ---- bf16 pack/unpack (RNE; values are finite) -----------------------------
__device__ __forceinline__ unsigned bf_rne(float x) {
    unsigned u = __float_as_uint(x);
    return (u + 0x7FFFu + ((u >> 16) & 1u)) >> 16;
}
__device__ __forceinline__ unsigned pack2(float lo, float hi) {
    return bf_rne(lo) | (bf_rne(hi) << 16);
}
__device__ __forceinline__ float lo_f(unsigned u) { return __uint_as_float(u << 16); }
__device__ __forceinline__ float hi_f(unsigned u) { return __uint_as_float(u & 0xFFFF0000u); }

// ---------------------------------------------------------------------------
// binpack body: tile counting-sort into 391 bucket-strided regions (one global
// atomic per bucket per tile at implicit base b*CAPB). packed = (src<<8)|dst&255.
// 512 threads.
// ---------------------------------------------------------------------------
__device__ void binpack_body(const int* __restrict__ src, const int* __restrict__ dst,
                             int E, int* __restrict__ cursor,
                             unsigned* __restrict__ packed, int bid) {
    __shared__ int hist[NBUCK];
    __shared__ int lofs[NBUCK];
    __shared__ int gbase[NBUCK];
    __shared__ int lcur[NBUCK];
    __shared__ int wsum[8];
    __shared__ unsigned stage[TILE];          // 16 KB
    __shared__ unsigned short sbuck[TILE];    // 8 KB
    int t  = threadIdx.x;
    int t0 = bid * TILE;
    int n  = min(TILE, E - t0);

    if (t < NBUCK) hist[t] = 0;
    __syncthreads();
    for (int i = t; i < n; i += 512) atomicAdd(&hist[dst[t0 + i] >> 8], 1);
    __syncthreads();
    int lane = t & 63, w = t >> 6;
    int v = (t < NBUCK) ? hist[t] : 0;
    int s = v;
#pragma unroll
    for (int off = 1; off < 64; off <<= 1) {
        int u = __shfl_up(s, off, 64);
        if (lane >= off) s += u;
    }
    if (lane == 63) wsum[w] = s;
    __syncthreads();
    if (t == 0) {
        int run = 0;
#pragma unroll
        for (int i = 0; i < 8; ++i) { int c = wsum[i]; wsum[i] = run; run += c; }
    }
    __syncthreads();
    if (t < NBUCK) {
        int ex = s - v + wsum[w];
        lofs[t] = ex;
        lcur[t] = ex;
        gbase[t] = t * CAPB + (v ? atomicAdd(&cursor[t], v) : 0);
    }
    __syncthreads();
    for (int i = t; i < n; i += 512) {
        int d = dst[t0 + i];
        int b = d >> 8;
        int p = atomicAdd(&lcur[b], 1);
        stage[p] = ((unsigned)src[t0 + i] << 8) | (unsigned)(d & 255);
        sbuck[p] = (unsigned short)b;
    }
    __syncthreads();
    for (int i = t; i < n; i += 512) {
        int b = sbuck[i];
        packed[gbase[b] + (i - lofs[b])] = stage[i];
    }
}

// ---------------------------------------------------------------------------
// gemm body: Ah = bf16(X @ W), UNSCALED. VALU-only loop (W column in 64 VGPRs,
// x broadcast via readlane). 512 threads = 8 waves x 4 rows = 32 rows/block.
// Adjacent-column pairing via shfl_xor(1); even lanes store packed uint.
// ---------------------------------------------------------------------------
__device__ void gemm_body(const float* __restrict__ X, const float* __restrict__ W,
                          unsigned* __restrict__ Ah, int bid) {
    __shared__ float wl[64 * 64];             // 16 KB, [k][col]
    int t = threadIdx.x;
    for (int i = t; i < 64 * 64; i += 512) wl[i] = W[i];
    __syncthreads();
    int lane = t & 63;
    int w    = t >> 6;
    float Wreg[64];
#pragma unroll
    for (int k = 0; k < 64; ++k) Wreg[k] = wl[k * 64 + lane];

    int row0 = bid * 32 + w * 4;
    const float* xp = X + (size_t)row0 * F;
    float xa = xp[lane];
    float xb = xp[64 + lane];
    float xc = xp[128 + lane];
    float xd = xp[192 + lane];
    float a0 = 0.f, a1 = 0.f, a2 = 0.f, a3 = 0.f;
#pragma unroll
    for (int k = 0; k < 64; ++k) {
        float wv = Wreg[k];
        a0 = fmaf(__uint_as_float(__builtin_amdgcn_readlane(__float_as_uint(xa), k)), wv, a0);
        a1 = fmaf(__uint_as_float(__builtin_amdgcn_readlane(__float_as_uint(xb), k)), wv, a1);
        a2 = fmaf(__uint_as_float(__builtin_amdgcn_readlane(__float_as_uint(xc), k)), wv, a2);
        a3 = fmaf(__uint_as_float(__builtin_amdgcn_readlane(__float_as_uint(xd), k)), wv, a3);
    }
    float p0 = __shfl_xor(a0, 1, 64);
    float p1 = __shfl_xor(a1, 1, 64);
    float p2 = __shfl_xor(a2, 1, 64);
    float p3 = __shfl_xor(a3, 1, 64);
    if (!(lane & 1)) {                        // even lane packs (col L, col L+1)
        int c = lane >> 1;
        Ah[(size_t)(row0 + 0) * 32 + c] = pack2(a0, p0);
        Ah[(size_t)(row0 + 1) * 32 + c] = pack2(a1, p1);
        Ah[(size_t)(row0 + 2) * 32 + c] = pack2(a2, p2);
        Ah[(size_t)(row0 + 3) * 32 + c] = pack2(a3, p3);
    }
}

// K1: binpack (blocks [0,nbp)) runs concurrently with layer-1 gemm (rest).
__global__ __launch_bounds__(512) void pre_gemm1(const int* __restrict__ src,
                                                 const int* __restrict__ dst, int E,
                                                 int nbp, int* __restrict__ cursor,
                                                 unsigned* __restrict__ packed,
                                                 const float* __restrict__ X,
                                                 const float* __restrict__ W1,
                                                 unsigned* __restrict__ Ah) {
    if ((int)blockIdx.x < nbp)
        binpack_body(src, dst, E, cursor, packed, blockIdx.x);
    else
        gemm_body(X, W1, Ah, blockIdx.x - nbp);
}

__global__ __launch_bounds__(512) void gemm_plain(const float* __restrict__ X,
                                                  const float* __restrict__ W,
                                                  unsigned* __restrict__ Ah) {
    gemm_body(X, W, Ah, blockIdx.x);
}

// ---------------------------------------------------------------------------
// Per-bucket LDS counting sort to node order; emits row_ptr (absolute), deg,
// dis = rsqrt(deg+1). srt stays bucket-strided.
// ---------------------------------------------------------------------------
__global__ __launch_bounds__(512) void node_sort(const unsigned* __restrict__ packed,
                                                 const int* __restrict__ cursor,
                                                 int* __restrict__ row_ptr,
                                                 int* __restrict__ deg,
                                                 float* __restrict__ dis,
                                                 int* __restrict__ srt) {
    __shared__ int h[256];
    __shared__ int lcur[256];
    __shared__ int wsum[4];
    __shared__ int stage[CAPB];               // 16 KB
    int b = blockIdx.x, t = threadIdx.x;
    int nbase = b << 8;
    int nloc = min(256, NN - nbase);
    int beg = b * CAPB;
    int n = cursor[b];

    if (t < 256) h[t] = 0;
    __syncthreads();
    for (int i = t; i < n; i += 512)
        atomicAdd(&h[packed[beg + i] & 255u], 1);
    __syncthreads();
    int lane = t & 63, w = t >> 6;
    int v = 0, s = 0;
    if (t < 256) { v = h[t]; s = v; }
#pragma unroll
    for (int off = 1; off < 64; off <<= 1) {
        int u = __shfl_up(s, off, 64);
        if (lane >= off) s += u;
    }
    if (t < 256 && lane == 63) wsum[w] = s;
    __syncthreads();
    if (t == 0) {
        int run = 0;
#pragma unroll
        for (int i = 0; i < 4; ++i) { int c = wsum[i]; wsum[i] = run; run += c; }
    }
    __syncthreads();
    if (t < 256) {
        int e0 = s - v + wsum[w];
        lcur[t] = e0;
        if (t < nloc) {
            row_ptr[nbase + t] = beg + e0;
            deg[nbase + t]     = v;
            dis[nbase + t]     = rsqrtf((float)v + 1.0f);   // +1 = self-loop
        }
    }
    __syncthreads();
    for (int i = t; i < n; i += 512) {
        unsigned p = packed[beg + i];
        int pos = atomicAdd(&lcur[p & 255u], 1);
        stage[pos] = (int)(p >> 8);
    }
    __syncthreads();
    for (int i = t; i < n; i += 512) srt[beg + i] = stage[i];
}

// ---------------------------------------------------------------------------
// Gather aggregation over bf16 A with per-edge dis[s] scaling + fused
// bias(+ReLU). 16 lanes/node (uint2 = 4 bf16/lane), 16 nodes/256-thr block.
// out[i] = (relu?)( b + dis_i*(dis_i*A[i] + sum_e dis[s_e]*A[s_e]) )
// ---------------------------------------------------------------------------
__global__ __launch_bounds__(256) void agg_out(const uint2* __restrict__ Ah2,
                                               const int* __restrict__ row_ptr,
                                               const int* __restrict__ deg,
                                               const int* __restrict__ srt,
                                               const float* __restrict__ dis,
                                               const float* __restrict__ bias,
                                               float4* __restrict__ out, int do_relu) {
    int sub  = threadIdx.x & 15;
    int node = blockIdx.x * 16 + (threadIdx.x >> 4);
    int beg = row_ptr[node];
    int end = beg + deg[node];
    float di = dis[node];
    uint2 su = Ah2[(size_t)node * 16 + sub];
    float4 acc;
    acc.x = di * lo_f(su.x);
    acc.y = di * hi_f(su.x);
    acc.z = di * lo_f(su.y);
    acc.w = di * hi_f(su.y);
    int j = beg;
    for (; j + 4 <= end; j += 4) {
        int s0 = srt[j], s1 = srt[j + 1], s2 = srt[j + 2], s3 = srt[j + 3];
        float d0 = dis[s0], d1 = dis[s1], d2 = dis[s2], d3 = dis[s3];
        uint2 g0 = Ah2[(size_t)s0 * 16 + sub];
        uint2 g1 = Ah2[(size_t)s1 * 16 + sub];
        uint2 g2 = Ah2[(size_t)s2 * 16 + sub];
        uint2 g3 = Ah2[(size_t)s3 * 16 + sub];
        acc.x = fmaf(d0, lo_f(g0.x), fmaf(d1, lo_f(g1.x), fmaf(d2, lo_f(g2.x), fmaf(d3, lo_f(g3.x), acc.x))));
        acc.y = fmaf(d0, hi_f(g0.x), fmaf(d1, hi_f(g1.x), fmaf(d2, hi_f(g2.x), fmaf(d3, hi_f(g3.x), acc.y))));
        acc.z = fmaf(d0, lo_f(g0.y), fmaf(d1, lo_f(g1.y), fmaf(d2, lo_f(g2.y), fmaf(d3, lo_f(g3.y), acc.z))));
        acc.w = fmaf(d0, hi_f(g0.y), fmaf(d1, hi_f(g1.y), fmaf(d2, hi_f(g2.y), fmaf(d3, hi_f(g3.y), acc.w))));
    }
    for (; j < end; ++j) {
        int s0 = srt[j];
        float d0 = dis[s0];
        uint2 g0 = Ah2[(size_t)s0 * 16 + sub];
        acc.x = fmaf(d0, lo_f(g0.x), acc.x);
        acc.y = fmaf(d0, hi_f(g0.x), acc.y);
        acc.z = fmaf(d0, lo_f(g0.y), acc.z);
        acc.w = fmaf(d0, hi_f(g0.y), acc.w);
    }
    float4 bb = ((const float4*)bias)[sub];
    float4 o;
    o.x = fmaf(di, acc.x, bb.x);
    o.y = fmaf(di, acc.y, bb.y);
    o.z = fmaf(di, acc.z, bb.z);
    o.w = fmaf(di, acc.w, bb.w);
    if (do_relu) {
        o.x = fmaxf(o.x, 0.f); o.y = fmaxf(o.y, 0.f);
        o.z = fmaxf(o.z, 0.f); o.w = fmaxf(o.w, 0.f);
    }
    out[(size_t)node * 16 + sub] = o;
}

extern "C" void kernel_launch(void* const* d_in, const int* in_sizes, int n_in,
                              void* d_out, int out_size, void* d_ws, size_t ws_size,
                              hipStream_t stream) {
    const float* x  = (const float*)d_in[0];
    const int*   ei = (const int*)d_in[1];   // [2,E]: src = ei[0:E], dst = ei[E:2E]
    const float* W1 = (const float*)d_in[2];
    const float* b1 = (const float*)d_in[3];
    const float* W2 = (const float*)d_in[4];
    const float* b2 = (const float*)d_in[5];
    float* out = (float*)d_out;
    int E = in_sizes[1] / 2;
    const int* src = ei;
    const int* dst = ei + E;

    int*      ws_i    = (int*)d_ws;
    int*      cursor  = ws_i + O_CURSOR;
    int*      row_ptr = ws_i + O_ROWPTR;
    int*      deg     = ws_i + O_DEG;
    float*    dis     = (float*)(ws_i + O_DIS);
    unsigned* packed  = (unsigned*)(ws_i + O_PACKED);
    int*      srt     = ws_i + O_SRT;
    unsigned* Ah      = (unsigned*)(ws_i + O_AH);

    int nbp = (E + TILE - 1) / TILE;

    hipMemsetAsync(cursor, 0, NBUCK * sizeof(int), stream);
    // K1: binpack (first nbp blocks) || layer-1 gemm (next 3125 blocks)
    pre_gemm1<<<nbp + NN / 32, 512, 0, stream>>>(src, dst, E, nbp, cursor, packed,
                                                 x, W1, Ah);
    node_sort<<<NBUCK, 512, 0, stream>>>(packed, cursor, row_ptr, deg, dis, srt);
    agg_out<<<NN / 16, 256, 0, stream>>>((const uint2*)Ah, row_ptr, deg, srt, dis,
                                         b1, (float4*)out, 1);
    gemm_plain<<<NN / 32, 512, 0, stream>>>(out, W2, Ah);
    agg_out<<<NN / 16, 256, 0, stream>>>((const uint2*)Ah, row_ptr, deg, srt, dis,
                                         b2, (float4*)out, 0);
}

// Round 9
// 213.345 us; speedup vs baseline: 1.7380x; 1.0833x over previous
//
#include <hip/hip_runtime.h>

#define NN    100000   // N_NODES
#define F     64       // feature dim (= hidden dim)
#define NBUCK 391      // ceil(NN/256) buckets of 256 nodes
#define CAPB  4096     // per-bucket edge capacity (mean 3197, 16-sigma margin)
#define TILE  4096     // edges per binpack tile

// workspace offsets (4-byte elements)
#define O_CURSOR 0          // int[391]
#define O_ROWPTR 512        // int[100000]  absolute index into srt
#define O_DEG    100864     // int[100000]
#define O_DIS    201216     // float[100000]
#define O_PACKED 301568     // uint[391*4096]
#define O_SRT    1903104    // int[391*4096 + 64]
#define O_AH     3504768    // uint[NN*32]: bf16-packed A rows (128 B/row)
#define O_HH     6704768    // uint[NN*32]: bf16-packed h rows (layer-1 output)

// ---- bf16 pack/unpack (RNE; values finite) --------------------------------
__device__ __forceinline__ unsigned bf_rne(float x) {
    unsigned u = __float_as_uint(x);
    return (u + 0x7FFFu + ((u >> 16) & 1u)) >> 16;
}
__device__ __forceinline__ unsigned pack2(float lo, float hi) {
    return bf_rne(lo) | (bf_rne(hi) << 16);
}
__device__ __forceinline__ float lo_f(unsigned u) { return __uint_as_float(u << 16); }
__device__ __forceinline__ float hi_f(unsigned u) { return __uint_as_float(u & 0xFFFF0000u); }

// ---- shared-memory union: binpack view || gemm view (per-block exclusive) --
struct BpSmem {
    int hist[NBUCK], lofs[NBUCK], gbase[NBUCK], lcur[NBUCK];
    int wsum[8];
    unsigned stage[TILE];                     // 16 KB
    unsigned short sbuck[TILE];               // 8 KB
};                                            // 30864 B
union KSmem {
    BpSmem bp;
    float wl[64 * 64];                        // 16 KB
};

// ---------------------------------------------------------------------------
// binpack body: tile counting-sort into 391 bucket-strided regions (one
// global atomic per bucket per tile at implicit base b*CAPB).
// packed = (src<<8) | (dst & 255). 512 threads.
// ---------------------------------------------------------------------------
__device__ __forceinline__ void binpack_body(const int* __restrict__ src,
                                             const int* __restrict__ dst, int E,
                                             int* __restrict__ cursor,
                                             unsigned* __restrict__ packed,
                                             int bid, BpSmem& sm) {
    int t  = threadIdx.x;
    int t0 = bid * TILE;
    int n  = min(TILE, E - t0);

    if (t < NBUCK) sm.hist[t] = 0;
    __syncthreads();
    for (int i = t; i < n; i += 512) atomicAdd(&sm.hist[dst[t0 + i] >> 8], 1);
    __syncthreads();
    int lane = t & 63, w = t >> 6;
    int v = (t < NBUCK) ? sm.hist[t] : 0;
    int s = v;
#pragma unroll
    for (int off = 1; off < 64; off <<= 1) {
        int u = __shfl_up(s, off, 64);
        if (lane >= off) s += u;
    }
    if (lane == 63) sm.wsum[w] = s;
    __syncthreads();
    if (t == 0) {
        int run = 0;
#pragma unroll
        for (int i = 0; i < 8; ++i) { int c = sm.wsum[i]; sm.wsum[i] = run; run += c; }
    }
    __syncthreads();
    if (t < NBUCK) {
        int ex = s - v + sm.wsum[w];
        sm.lofs[t] = ex;
        sm.lcur[t] = ex;
        sm.gbase[t] = t * CAPB + (v ? atomicAdd(&cursor[t], v) : 0);
    }
    __syncthreads();
    for (int i = t; i < n; i += 512) {
        int d = dst[t0 + i];
        int b = d >> 8;
        int p = atomicAdd(&sm.lcur[b], 1);
        sm.stage[p] = ((unsigned)src[t0 + i] << 8) | (unsigned)(d & 255);
        sm.sbuck[p] = (unsigned short)b;
    }
    __syncthreads();
    for (int i = t; i < n; i += 512) {
        int b = sm.sbuck[i];
        packed[sm.gbase[b] + (i - sm.lofs[b])] = sm.stage[i];
    }
}

// ---------------------------------------------------------------------------
// gemm body (f32 X): Ah = bf16(X @ W). VALU loop, x broadcast via readlane.
// 512 thr = 8 waves x 4 rows = 32 rows/block. Even lanes pack col pairs.
// ---------------------------------------------------------------------------
__device__ __forceinline__ void gemm_body(const float* __restrict__ X,
                                          const float* __restrict__ W,
                                          unsigned* __restrict__ Ah, int bid,
                                          float* wl) {
    int t = threadIdx.x;
    for (int i = t; i < 64 * 64; i += 512) wl[i] = W[i];
    __syncthreads();
    int lane = t & 63;
    int w    = t >> 6;
    float Wreg[64];
#pragma unroll
    for (int k = 0; k < 64; ++k) Wreg[k] = wl[k * 64 + lane];

    int row0 = bid * 32 + w * 4;
    const float* xp = X + (size_t)row0 * F;
    float xa = xp[lane];
    float xb = xp[64 + lane];
    float xc = xp[128 + lane];
    float xd = xp[192 + lane];
    float a0 = 0.f, a1 = 0.f, a2 = 0.f, a3 = 0.f;
#pragma unroll
    for (int k = 0; k < 64; ++k) {
        float wv = Wreg[k];
        a0 = fmaf(__uint_as_float(__builtin_amdgcn_readlane(__float_as_uint(xa), k)), wv, a0);
        a1 = fmaf(__uint_as_float(__builtin_amdgcn_readlane(__float_as_uint(xb), k)), wv, a1);
        a2 = fmaf(__uint_as_float(__builtin_amdgcn_readlane(__float_as_uint(xc), k)), wv, a2);
        a3 = fmaf(__uint_as_float(__builtin_amdgcn_readlane(__float_as_uint(xd), k)), wv, a3);
    }
    float p0 = __shfl_xor(a0, 1, 64);
    float p1 = __shfl_xor(a1, 1, 64);
    float p2 = __shfl_xor(a2, 1, 64);
    float p3 = __shfl_xor(a3, 1, 64);
    if (!(lane & 1)) {
        int c = lane >> 1;
        Ah[(size_t)(row0 + 0) * 32 + c] = pack2(a0, p0);
        Ah[(size_t)(row0 + 1) * 32 + c] = pack2(a1, p1);
        Ah[(size_t)(row0 + 2) * 32 + c] = pack2(a2, p2);
        Ah[(size_t)(row0 + 3) * 32 + c] = pack2(a3, p3);
    }
}

// ---------------------------------------------------------------------------
// gemm body (bf16-packed H input): Ah = bf16(H @ W). Lane loads packed col
// pairs; readlane + compile-time lo/hi select broadcasts h[row][k].
// pa holds rows 0-1 (lanes 0-31 / 32-63), pb rows 2-3.
// ---------------------------------------------------------------------------
__device__ __forceinline__ void gemm_h_body(const unsigned* __restrict__ Hh,
                                            const float* __restrict__ W,
                                            unsigned* __restrict__ Ah, int bid,
                                            float* wl) {
    int t = threadIdx.x;
    for (int i = t; i < 64 * 64; i += 512) wl[i] = W[i];
    __syncthreads();
    int lane = t & 63;
    int w    = t >> 6;
    float Wreg[64];
#pragma unroll
    for (int k = 0; k < 64; ++k) Wreg[k] = wl[k * 64 + lane];

    int row0 = bid * 32 + w * 4;
    int l = lane & 31, r = lane >> 5;
    unsigned pa = Hh[(size_t)(row0 + r) * 32 + l];        // rows 0,1
    unsigned pb = Hh[(size_t)(row0 + 2 + r) * 32 + l];    // rows 2,3
    float a0 = 0.f, a1 = 0.f, a2 = 0.f, a3 = 0.f;
#pragma unroll
    for (int k = 0; k < 64; ++k) {
        float wv = Wreg[k];
        unsigned q0 = __builtin_amdgcn_readlane(pa, k >> 1);
        unsigned q1 = __builtin_amdgcn_readlane(pa, 32 + (k >> 1));
        unsigned q2 = __builtin_amdgcn_readlane(pb, k >> 1);
        unsigned q3 = __builtin_amdgcn_readlane(pb, 32 + (k >> 1));
        float x0 = (k & 1) ? hi_f(q0) : lo_f(q0);
        float x1 = (k & 1) ? hi_f(q1) : lo_f(q1);
        float x2 = (k & 1) ? hi_f(q2) : lo_f(q2);
        float x3 = (k & 1) ? hi_f(q3) : lo_f(q3);
        a0 = fmaf(x0, wv, a0);
        a1 = fmaf(x1, wv, a1);
        a2 = fmaf(x2, wv, a2);
        a3 = fmaf(x3, wv, a3);
    }
    float p0 = __shfl_xor(a0, 1, 64);
    float p1 = __shfl_xor(a1, 1, 64);
    float p2 = __shfl_xor(a2, 1, 64);
    float p3 = __shfl_xor(a3, 1, 64);
    if (!(lane & 1)) {
        int c = lane >> 1;
        Ah[(size_t)(row0 + 0) * 32 + c] = pack2(a0, p0);
        Ah[(size_t)(row0 + 1) * 32 + c] = pack2(a1, p1);
        Ah[(size_t)(row0 + 2) * 32 + c] = pack2(a2, p2);
        Ah[(size_t)(row0 + 3) * 32 + c] = pack2(a3, p3);
    }
}

// K1: binpack (blocks [0,nbp)) || layer-1 gemm (rest). LDS = union (30.9 KB).
__global__ __launch_bounds__(512) void pre_gemm1(const int* __restrict__ src,
                                                 const int* __restrict__ dst, int E,
                                                 int nbp, int* __restrict__ cursor,
                                                 unsigned* __restrict__ packed,
                                                 const float* __restrict__ X,
                                                 const float* __restrict__ W1,
                                                 unsigned* __restrict__ Ah) {
    __shared__ KSmem sm;
    if ((int)blockIdx.x < nbp)
        binpack_body(src, dst, E, cursor, packed, blockIdx.x, sm.bp);
    else
        gemm_body(X, W1, Ah, blockIdx.x - nbp, sm.wl);
}

__global__ __launch_bounds__(512) void gemm2h(const unsigned* __restrict__ Hh,
                                              const float* __restrict__ W,
                                              unsigned* __restrict__ Ah) {
    __shared__ float wl[64 * 64];
    gemm_h_body(Hh, W, Ah, blockIdx.x, wl);
}

// ---------------------------------------------------------------------------
// Per-bucket LDS counting sort to node order; emits row_ptr (absolute), deg,
// dis = rsqrt(deg+1). srt stays bucket-strided.
// ---------------------------------------------------------------------------
__global__ __launch_bounds__(512) void node_sort(const unsigned* __restrict__ packed,
                                                 const int* __restrict__ cursor,
                                                 int* __restrict__ row_ptr,
                                                 int* __restrict__ deg,
                                                 float* __restrict__ dis,
                                                 int* __restrict__ srt) {
    __shared__ int h[256];
    __shared__ int lcur[256];
    __shared__ int wsum[4];
    __shared__ int stage[CAPB];               // 16 KB
    int b = blockIdx.x, t = threadIdx.x;
    int nbase = b << 8;
    int nloc = min(256, NN - nbase);
    int beg = b * CAPB;
    int n = cursor[b];

    if (t < 256) h[t] = 0;
    __syncthreads();
    for (int i = t; i < n; i += 512)
        atomicAdd(&h[packed[beg + i] & 255u], 1);
    __syncthreads();
    int lane = t & 63, w = t >> 6;
    int v = 0, s = 0;
    if (t < 256) { v = h[t]; s = v; }
#pragma unroll
    for (int off = 1; off < 64; off <<= 1) {
        int u = __shfl_up(s, off, 64);
        if (lane >= off) s += u;
    }
    if (t < 256 && lane == 63) wsum[w] = s;
    __syncthreads();
    if (t == 0) {
        int run = 0;
#pragma unroll
        for (int i = 0; i < 4; ++i) { int c = wsum[i]; wsum[i] = run; run += c; }
    }
    __syncthreads();
    if (t < 256) {
        int e0 = s - v + wsum[w];
        lcur[t] = e0;
        if (t < nloc) {
            row_ptr[nbase + t] = beg + e0;
            deg[nbase + t]     = v;
            dis[nbase + t]     = rsqrtf((float)v + 1.0f);   // +1 = self-loop
        }
    }
    __syncthreads();
    for (int i = t; i < n; i += 512) {
        unsigned p = packed[beg + i];
        int pos = atomicAdd(&lcur[p & 255u], 1);
        stage[pos] = (int)(p >> 8);
    }
    __syncthreads();
    for (int i = t; i < n; i += 512) srt[beg + i] = stage[i];
}

// ---------------------------------------------------------------------------
// Gather aggregation over bf16 A with per-edge dis[s] + fused bias.
// MODE 1: ReLU + write bf16-packed h (uint2).  MODE 0: write float4 out.
// 16 lanes/node (4 bf16 cols/lane), 16 nodes per 256-thread block.
// ---------------------------------------------------------------------------
template <int MODE>
__global__ __launch_bounds__(256) void agg_out(const uint2* __restrict__ Ah2,
                                               const int* __restrict__ row_ptr,
                                               const int* __restrict__ deg,
                                               const int* __restrict__ srt,
                                               const float* __restrict__ dis,
                                               const float* __restrict__ bias,
                                               void* __restrict__ outp) {
    int sub  = threadIdx.x & 15;
    int node = blockIdx.x * 16 + (threadIdx.x >> 4);
    int beg = row_ptr[node];
    int end = beg + deg[node];
    float di = dis[node];
    uint2 su = Ah2[(size_t)node * 16 + sub];
    float4 acc;
    acc.x = di * lo_f(su.x);
    acc.y = di * hi_f(su.x);
    acc.z = di * lo_f(su.y);
    acc.w = di * hi_f(su.y);
    int j = beg;
    for (; j + 4 <= end; j += 4) {
        int s0 = srt[j], s1 = srt[j + 1], s2 = srt[j + 2], s3 = srt[j + 3];
        float d0 = dis[s0], d1 = dis[s1], d2 = dis[s2], d3 = dis[s3];
        uint2 g0 = Ah2[(size_t)s0 * 16 + sub];
        uint2 g1 = Ah2[(size_t)s1 * 16 + sub];
        uint2 g2 = Ah2[(size_t)s2 * 16 + sub];
        uint2 g3 = Ah2[(size_t)s3 * 16 + sub];
        acc.x = fmaf(d0, lo_f(g0.x), fmaf(d1, lo_f(g1.x), fmaf(d2, lo_f(g2.x), fmaf(d3, lo_f(g3.x), acc.x))));
        acc.y = fmaf(d0, hi_f(g0.x), fmaf(d1, hi_f(g1.x), fmaf(d2, hi_f(g2.x), fmaf(d3, hi_f(g3.x), acc.y))));
        acc.z = fmaf(d0, lo_f(g0.y), fmaf(d1, lo_f(g1.y), fmaf(d2, lo_f(g2.y), fmaf(d3, lo_f(g3.y), acc.z))));
        acc.w = fmaf(d0, hi_f(g0.y), fmaf(d1, hi_f(g1.y), fmaf(d2, hi_f(g2.y), fmaf(d3, hi_f(g3.y), acc.w))));
    }
    for (; j < end; ++j) {
        int s0 = srt[j];
        float d0 = dis[s0];
        uint2 g0 = Ah2[(size_t)s0 * 16 + sub];
        acc.x = fmaf(d0, lo_f(g0.x), acc.x);
        acc.y = fmaf(d0, hi_f(g0.x), acc.y);
        acc.z = fmaf(d0, lo_f(g0.y), acc.z);
        acc.w = fmaf(d0, hi_f(g0.y), acc.w);
    }
    float4 bb = ((const float4*)bias)[sub];
    float4 o;
    o.x = fmaf(di, acc.x, bb.x);
    o.y = fmaf(di, acc.y, bb.y);
    o.z = fmaf(di, acc.z, bb.z);
    o.w = fmaf(di, acc.w, bb.w);
    if (MODE == 1) {
        o.x = fmaxf(o.x, 0.f); o.y = fmaxf(o.y, 0.f);
        o.z = fmaxf(o.z, 0.f); o.w = fmaxf(o.w, 0.f);
        uint2 pk;
        pk.x = pack2(o.x, o.y);
        pk.y = pack2(o.z, o.w);
        ((uint2*)outp)[(size_t)node * 16 + sub] = pk;
    } else {
        ((float4*)outp)[(size_t)node * 16 + sub] = o;
    }
}

extern "C" void kernel_launch(void* const* d_in, const int* in_sizes, int n_in,
                              void* d_out, int out_size, void* d_ws, size_t ws_size,
                              hipStream_t stream) {
    const float* x  = (const float*)d_in[0];
    const int*   ei = (const int*)d_in[1];   // [2,E]: src = ei[0:E], dst = ei[E:2E]
    const float* W1 = (const float*)d_in[2];
    const float* b1 = (const float*)d_in[3];
    const float* W2 = (const float*)d_in[4];
    const float* b2 = (const float*)d_in[5];
    float* out = (float*)d_out;
    int E = in_sizes[1] / 2;
    const int* src = ei;
    const int* dst = ei + E;

    int*      ws_i    = (int*)d_ws;
    int*      cursor  = ws_i + O_CURSOR;
    int*      row_ptr = ws_i + O_ROWPTR;
    int*      deg     = ws_i + O_DEG;
    float*    dis     = (float*)(ws_i + O_DIS);
    unsigned* packed  = (unsigned*)(ws_i + O_PACKED);
    int*      srt     = ws_i + O_SRT;
    unsigned* Ah      = (unsigned*)(ws_i + O_AH);
    unsigned* Hh      = (unsigned*)(ws_i + O_HH);

    int nbp = (E + TILE - 1) / TILE;

    hipMemsetAsync(cursor, 0, NBUCK * sizeof(int), stream);
    // K1: binpack (first nbp blocks) || layer-1 gemm (next 3125 blocks)
    pre_gemm1<<<nbp + NN / 32, 512, 0, stream>>>(src, dst, E, nbp, cursor, packed,
                                                 x, W1, Ah);
    node_sort<<<NBUCK, 512, 0, stream>>>(packed, cursor, row_ptr, deg, dis, srt);
    // layer 1 aggregate -> bf16 h
    agg_out<1><<<NN / 16, 256, 0, stream>>>((const uint2*)Ah, row_ptr, deg, srt,
                                            dis, b1, Hh);
    // layer 2 gemm (bf16 h input) -> bf16 Ah
    gemm2h<<<NN / 32, 512, 0, stream>>>(Hh, W2, Ah);
    // layer 2 aggregate -> f32 out
    agg_out<0><<<NN / 16, 256, 0, stream>>>((const uint2*)Ah, row_ptr, deg, srt,
                                            dis, b2, out);
}